// Round 7
// baseline (414.854 us; speedup 1.0000x reference)
//
#include <hip/hip_runtime.h>
#include <float.h>

#define LSEQ 1024
#define NCH  8192   // B*H*d = 16*8*64
#define TOPK 13     // int(2*ln(1024))
#define KPAD 1088   // 1024 + 1024/16 padding (addr(f) = f + (f>>4))

__device__ __forceinline__ float rdlane(float v, unsigned l) {
  return __uint_as_float(__builtin_amdgcn_readlane(__float_as_uint(v), l));
}

// ---- Tiled transpose: in[b][r][c] -> out[b][c][r] -------------------------
__global__ __launch_bounds__(256) void transpose_rc(const float* __restrict__ in,
                                                    float* __restrict__ out,
                                                    int rows, int cols) {
  __shared__ float tile[32][33];
  int b  = blockIdx.z;
  int r0 = blockIdx.y * 32, c0 = blockIdx.x * 32;
  const float* src = in  + (size_t)b * rows * cols;
  float*       dst = out + (size_t)b * rows * cols;
  int tx = threadIdx.x, ty = threadIdx.y;   // block (32,8)
#pragma unroll
  for (int j = 0; j < 32; j += 8)
    tile[ty + j][tx] = src[(size_t)(r0 + ty + j) * cols + (c0 + tx)];
  __syncthreads();
#pragma unroll
  for (int j = 0; j < 32; j += 8)
    dst[(size_t)(c0 + ty + j) * rows + (r0 + tx)] = tile[tx][ty + j];
}

// ---- Merged Q+K transpose (one launch, z in [0,32)) -----------------------
__global__ __launch_bounds__(256) void transpose_qk(const float* __restrict__ Q,
                                                    const float* __restrict__ K,
                                                    float* __restrict__ qT,
                                                    float* __restrict__ kT) {
  __shared__ float tile[32][33];
  int zz = blockIdx.z;
  const float* in  = (zz < 16) ? Q  : K;
  float*       out = (zz < 16) ? qT : kT;
  int b = zz & 15;
  const int rows = 1024, cols = 512;
  int r0 = blockIdx.y * 32, c0 = blockIdx.x * 32;
  const float* src = in  + (size_t)b * rows * cols;
  float*       dst = out + (size_t)b * rows * cols;
  int tx = threadIdx.x, ty = threadIdx.y;
#pragma unroll
  for (int j = 0; j < 32; j += 8)
    tile[ty + j][tx] = src[(size_t)(r0 + ty + j) * cols + (c0 + tx)];
  __syncthreads();
#pragma unroll
  for (int j = 0; j < 32; j += 8)
    dst[(size_t)(c0 + ty + j) * rows + (r0 + tx)] = tile[tx][ty + j];
}

// ---- Fused circular correlation + top-13 + softmax ------------------------
// One wave per channel; lane owns 16 consecutive taus. k in padded LDS
// (addr f+(f>>4), conflict-free b32 — R4). k window in a mod-32 circular
// register buffer, 8-phase-unrolled (static indices, R5). q row preloaded in
// 16 VGPRs, broadcast via v_readlane (R6). R7 FIX: __launch_bounds__(256,4).
// R4-R6 plateaued at ~2.4x the FMA floor because the default occupancy
// heuristic capped VGPRs below the loop's named state (cb32+acc16+vqs16+
// temps ~85 > VGPR_Count 68 in R6 -> forced spill/remat, inflating VALU by
// ~2x). 4 waves/EU -> 128-VGPR budget: everything registerizes.
__global__ __launch_bounds__(256, 4) void corr_topk_kernel(const float* __restrict__ qT,
                                                           const float* __restrict__ kT,
                                                           float* __restrict__ wout,
                                                           int* __restrict__ iout) {
  __shared__ float kpad[4][KPAD];
  int wave = threadIdx.x >> 6, lane = threadIdx.x & 63;
  int c = blockIdx.x * 4 + wave;
  float* kp = kpad[wave];

  // Stage k into padded LDS. Own wave's data only -> no __syncthreads.
  {
    const float4* k4 = (const float4*)(kT + (size_t)c * LSEQ);
#pragma unroll
    for (int j = 0; j < 4; ++j) {
      int q = lane + 64 * j;          // quad index
      float4 kv = k4[q];
      int a = 4 * q + (q >> 2);       // padded addr (quad never crosses a pad)
      kp[a] = kv.x; kp[a + 1] = kv.y; kp[a + 2] = kv.z; kp[a + 3] = kv.w;
    }
  }
  // Preload whole q row into registers: chunk j, lane l holds q[256j+4l..+3].
  const float4* q4r = (const float4*)(qT + (size_t)c * LSEQ);
  float4 vqs[4];
#pragma unroll
  for (int j = 0; j < 4; ++j) vqs[j] = q4r[lane + 64 * j];

  // cb[(g + 4t) & 31] holds k[(F + g + 4t) & 1023]; F = 1008 - 16*lane.
  int F = 1008 - 16 * lane;
  float cb[32];
#pragma unroll
  for (int g = 0; g < 20; ++g) {
    int gg = (F + g) & 1023;
    cb[g] = kp[gg + (gg >> 4)];
  }
  float acc[16];
#pragma unroll
  for (int i = 0; i < 16; ++i) acc[i] = 0.f;

  int gq = (F + 20) & 1023;           // next k element to load (use, then +=4)

#pragma unroll
  for (int T = 0; T < 4; ++T) {       // UNROLLED: vqs[T] statically indexed
    float4 VQ = vqs[T];
#pragma unroll 1
    for (int m = 0; m < 8; ++m) {     // rolled: keeps body ~5KB in L1I
      unsigned lb = (unsigned)(m * 8);  // uniform -> SGPR
#pragma unroll
      for (int p = 0; p < 8; ++p) {   // cb phase period (4*8 == 32)
        float qx = rdlane(VQ.x, lb + p);
        float qy = rdlane(VQ.y, lb + p);
        float qz = rdlane(VQ.z, lb + p);
        float qw = rdlane(VQ.w, lb + p);
#pragma unroll
        for (int i = 0; i < 16; ++i) {
          acc[i] += qx * cb[(4 * p + 16 - i) & 31];
          acc[i] += qy * cb[(4 * p + 17 - i) & 31];
          acc[i] += qz * cb[(4 * p + 18 - i) & 31];
          acc[i] += qw * cb[(4 * p + 19 - i) & 31];
        }
        int a0 = gq + (gq >> 4);      // quad never crosses a pad (gq%4==0)
        cb[(4 * p + 20) & 31] = kp[a0];
        cb[(4 * p + 21) & 31] = kp[a0 + 1];
        cb[(4 * p + 22) & 31] = kp[a0 + 2];
        cb[(4 * p + 23) & 31] = kp[a0 + 3];
        gq = (gq + 4) & 1023;
      }
    }
  }

  // ---- in-register top-13 (ties -> lowest index, matching lax.top_k) ----
  float topv[TOPK]; int topi[TOPK];
  for (int r = 0; r < TOPK; ++r) {
    float m = -FLT_MAX; int mi = 0x7fffffff;
#pragma unroll
    for (int j = 0; j < 16; ++j) {
      int idx = 16 * lane + j;
      if (acc[j] > m || (acc[j] == m && idx < mi)) { m = acc[j]; mi = idx; }
    }
#pragma unroll
    for (int off = 32; off >= 1; off >>= 1) {
      float om = __shfl_xor(m, off);
      int   oi = __shfl_xor(mi, off);
      if (om > m || (om == m && oi < mi)) { m = om; mi = oi; }
    }
    topv[r] = m; topi[r] = mi;
#pragma unroll
    for (int j = 0; j < 16; ++j)        // static-indexed knockout
      acc[j] = (16 * lane + j == mi) ? -FLT_MAX : acc[j];
  }
  float mx = topv[0];
  float wv[TOPK]; float wsum = 0.f;
#pragma unroll
  for (int r = 0; r < TOPK; ++r) { wv[r] = __expf(topv[r] - mx); wsum += wv[r]; }
  float inv = 1.0f / wsum;
  if (lane == 0) {
#pragma unroll
    for (int r = 0; r < TOPK; ++r) {
      wout[(size_t)c * 16 + r] = wv[r] * inv;
      iout[(size_t)c * 16 + r] = topi[r];
    }
  }
}

// ---- Time-delay aggregation: outT[c][t] = sum_i w_i * v[min(idx_i+t,L-1)] -
__global__ __launch_bounds__(256) void agg_kernel(const float* __restrict__ vT,
                                                  const float* __restrict__ wbuf,
                                                  const int* __restrict__ ibuf,
                                                  float* __restrict__ outT) {
  __shared__ float v2[2 * LSEQ];     // clamped extension: v2[j>=1024] = v[1023]
  __shared__ float ws[TOPK];
  __shared__ int   is[TOPK];
  int c = blockIdx.x, tid = threadIdx.x;
  const float* v = vT + (size_t)c * LSEQ;
  float last = v[LSEQ - 1];
  float4 vv = ((const float4*)v)[tid];
  ((float4*)v2)[tid]       = vv;
  ((float4*)v2)[tid + 256] = make_float4(last, last, last, last);
  if (tid < TOPK) { ws[tid] = wbuf[(size_t)c * 16 + tid]; is[tid] = ibuf[(size_t)c * 16 + tid]; }
  __syncthreads();
  float a0 = 0.f, a1 = 0.f, a2 = 0.f, a3 = 0.f;
#pragma unroll
  for (int i = 0; i < TOPK; ++i) {
    float wi = ws[i]; int di = is[i];
    a0 += wi * v2[di + tid];
    a1 += wi * v2[di + tid + 256];
    a2 += wi * v2[di + tid + 512];
    a3 += wi * v2[di + tid + 768];
  }
  float* o = outT + (size_t)c * LSEQ + tid;
  o[0] = a0; o[256] = a1; o[512] = a2; o[768] = a3;
}

extern "C" void kernel_launch(void* const* d_in, const int* in_sizes, int n_in,
                              void* d_out, int out_size, void* d_ws, size_t ws_size,
                              hipStream_t stream) {
  const float* Q = (const float*)d_in[0];
  const float* K = (const float*)d_in[1];
  const float* V = (const float*)d_in[2];
  float* out = (float*)d_out;
  float* ws  = (float*)d_ws;
  // ws layout (floats): bufA[8192*1024] | bufB[8192*1024] | w[8192*16] | idx[8192*16]
  float* bufA = ws;
  float* bufB = ws + (size_t)NCH * LSEQ;
  float* wbuf = ws + (size_t)2 * NCH * LSEQ;
  int*   ibuf = (int*)(wbuf + (size_t)NCH * 16);

  dim3 tb(32, 8);
  transpose_qk<<<dim3(16, 32, 32), tb, 0, stream>>>(Q, K, bufA, bufB);    // qT, kT
  corr_topk_kernel<<<NCH / 4, 256, 0, stream>>>(bufA, bufB, wbuf, ibuf);
  transpose_rc<<<dim3(16, 32, 16), tb, 0, stream>>>(V, bufA, 1024, 512);  // vT (qT dead)
  agg_kernel<<<NCH, 256, 0, stream>>>(bufA, wbuf, ibuf, bufB);            // outT (kT dead)
  transpose_rc<<<dim3(32, 16, 16), tb, 0, stream>>>(bufB, out, 512, 1024);
}